// Round 8
// baseline (168.190 us; speedup 1.0000x reference)
//
#include <hip/hip_runtime.h>

// GraphSAGE fused layer: out[B,128] = relu(concat(feat[nodes], mean_s feat[neigh])[B,256] @ W[256,128])
// B=50000, S=10, D=128, H=128. fp32 in/out; bf16 MFMA (threshold allows bf16).
//
// R8: async gather. R6/R7 showed the VGPR-load gather is latency-serialized
// (compiler collapses MLP to a few loads in flight; VGPR=28-36). Replace with
// global_load_lds width=16: per sub-phase each wave stages its output row's
// 11 source rows (self + 10 neigh, 512 B each) into a 45 KB LDS blob with 6
// async 1 KB instructions (no dest VGPRs -> all in flight), syncthreads
// drains, then a conflict-free float2 sum pass writes the bf16 GEMM tile.
// Two 8-row sub-phases per 16-row block; LDS 53504 B -> 3 blocks/CU.

typedef __attribute__((ext_vector_type(8))) short bf16x8;   // 8 bf16 (4 VGPRs)
typedef __attribute__((ext_vector_type(4))) float f32x4;    // MFMA C/D frag

typedef __attribute__((address_space(1))) const float gfloat;
typedef __attribute__((address_space(3))) float lfloat;

__device__ __forceinline__ unsigned short f2bf(float x) {
  unsigned int u = __float_as_uint(x);
  u += 0x7fffu + ((u >> 16) & 1u);
  return (unsigned short)(u >> 16);
}
__device__ __forceinline__ unsigned int pack2bf(float lo, float hi) {
  return (unsigned int)f2bf(lo) | ((unsigned int)f2bf(hi) << 16);
}

// W [K=256][H=128] fp32 row-major -> Wt [H=128][K=256] bf16 (once, to ws).
__global__ void sage_prep_wt(const float* __restrict__ W,
                             unsigned short* __restrict__ Wt) {
  int tid = blockIdx.x * blockDim.x + threadIdx.x;   // 0..8191 (float4 units)
  float4 v = ((const float4*)W)[tid];
  int flat = tid << 2;
  int k = flat >> 7;          // / H
  int h = flat & 127;         // % H
  Wt[(h + 0) * 256 + k] = f2bf(v.x);
  Wt[(h + 1) * 256 + k] = f2bf(v.y);
  Wt[(h + 2) * 256 + k] = f2bf(v.z);
  Wt[(h + 3) * 256 + k] = f2bf(v.w);
}

__global__ __launch_bounds__(512, 6)
void sage_fused5(const int* __restrict__ nodes,
                 const int* __restrict__ neigh,
                 const float* __restrict__ feat,
                 const unsigned short* __restrict__ Wt,
                 float* __restrict__ out, int B)
{
  constexpr int K = 256, H = 128, S = 10;
  constexpr int TILE = 16;
  constexpr int STR = K + 8;                     // 264 ushort = 528 B rows (bank shift 4)
  __shared__ float stage[8 * 11 * 128];          // 45056 B: 8 rows x 11 src x 128 fp32
  __shared__ unsigned short tile[TILE * STR];    // 8448 B bf16 GEMM tile

  const int t = threadIdx.x;
  const int lane = t & 63;
  const int wave = t >> 6;                       // 0..7
  const int block0 = blockIdx.x * TILE;

  for (int p = 0; p < 2; ++p) {
    // ---- stage: wave w -> output row p*8+w, 11 source rows async to LDS ----
    {
      int b = block0 + p * 8 + wave;
      if (b >= B) b = B - 1;                     // clamp (stores are guarded)
      int idx[11];
      idx[0] = nodes[b];
#pragma unroll
      for (int s = 0; s < S; ++s) idx[s + 1] = neigh[(long)b * S + s];

      const int stbase = wave * (11 * 128);      // float offset of this wave's blob
      const int half = lane >> 5;                // 0 lanes 0-31, 1 lanes 32-63
      const int col4 = (lane & 31) * 4;          // float offset within source row
#pragma unroll
      for (int j = 0; j < 5; ++j) {
        // instruction j stages source rows 2j (lanes 0-31) and 2j+1 (lanes 32-63)
        int sidx = half ? idx[2 * j + 1] : idx[2 * j];
        const float* g = feat + (long)sidx * 128 + col4;
        lfloat* l = (lfloat*)&stage[stbase + j * 256];   // wave-uniform base; HW adds lane*16
        __builtin_amdgcn_global_load_lds((gfloat*)g, l, 16, 0, 0);
      }
      if (lane < 32) {                           // source row 10 (half instruction)
        const float* g = feat + (long)idx[10] * 128 + col4;
        lfloat* l = (lfloat*)&stage[stbase + 5 * 256];
        __builtin_amdgcn_global_load_lds((gfloat*)g, l, 16, 0, 0);
      }
    }
    __syncthreads();   // drains vmcnt (async loads) + barrier

    // ---- sum: wave w reduces its blob -> tile row p*8+w (bf16) ----
    {
      const int stbase = wave * (11 * 128);
      const int e2 = lane * 2;                   // 2 elems/thread, stride-1 float2
      float2 self = *(const float2*)&stage[stbase + e2];
      float sx = 0.f, sy = 0.f;
#pragma unroll
      for (int s = 1; s <= S; ++s) {
        float2 v = *(const float2*)&stage[stbase + s * 128 + e2];
        sx += v.x; sy += v.y;
      }
      unsigned short* crow = &tile[(p * 8 + wave) * STR];
      *(unsigned int*)&crow[e2]       = pack2bf(self.x, self.y);
      *(unsigned int*)&crow[128 + e2] = pack2bf(sx * 0.1f, sy * 0.1f);
    }
    __syncthreads();   // p=0: staging reusable; p=1: tile complete
  }
  __builtin_amdgcn_sched_barrier(0);   // keep Wt loads out of gather lifetime

  // ---- MFMA: 8 waves x (16 rows x 16 cols) ----
  const int m    = lane & 15;
  const int quad = lane >> 4;
  const int cbase = wave * 16;                   // 8 waves x 16 = 128 cols

  bf16x8 bfrag[8];
#pragma unroll
  for (int ks = 0; ks < 8; ++ks)
    bfrag[ks] = *(const bf16x8*)&Wt[(cbase + m) * K + ks * 32 + quad * 8];

  f32x4 acc = {0.f, 0.f, 0.f, 0.f};
#pragma unroll
  for (int ks = 0; ks < 8; ++ks) {
    bf16x8 a = *(const bf16x8*)&tile[m * STR + ks * 32 + quad * 8];
    acc = __builtin_amdgcn_mfma_f32_16x16x32_bf16(a, bfrag[ks], acc, 0, 0, 0);
  }

  // C/D layout: col = lane&15, row = quad*4 + reg (verified m89/m91)
#pragma unroll
  for (int reg = 0; reg < 4; ++reg) {
    const int gb = block0 + quad * 4 + reg;
    if (gb < B) out[(size_t)gb * H + cbase + m] = fmaxf(acc[reg], 0.0f);
  }
}

extern "C" void kernel_launch(void* const* d_in, const int* in_sizes, int n_in,
                              void* d_out, int out_size, void* d_ws, size_t ws_size,
                              hipStream_t stream) {
  const int*   nodes = (const int*)d_in[0];
  const int*   neigh = (const int*)d_in[1];
  const float* feat  = (const float*)d_in[2];
  const float* W     = (const float*)d_in[3];
  float*       out   = (float*)d_out;
  const int B = in_sizes[0];                       // 50000

  unsigned short* Wt = (unsigned short*)d_ws;      // 64 KB
  sage_prep_wt<<<32, 256, 0, stream>>>(W, Wt);
  const int grid = (B + 15) / 16;                  // 3125
  sage_fused5<<<grid, 512, 0, stream>>>(nodes, neigh, feat, Wt, out, B);
}

// Round 9
// 129.975 us; speedup vs baseline: 1.2940x; 1.2940x over previous
//
#include <hip/hip_runtime.h>

// GraphSAGE fused layer: out[B,128] = relu(concat(feat[nodes], mean_s feat[neigh])[B,256] @ W[256,128])
// B=50000, S=10, D=128, H=128. fp32 in/out; bf16 MFMA (threshold allows bf16).
//
// R9: R6 structure (best fused gather: 47 us) + block-level index staging.
// Phase 0 stages all 352 block indices (contiguous neigh[block0*10 .. +320)
// and nodes[block0 .. +32)) into LDS with coalesced loads; the gather phase
// reads them via broadcast ds_read. Kills the 16x-redundant per-lane index
// global loads (~45% of gather VMEM instructions) and removes the idx->feat
// global dependency chain from the per-thread critical path.
// R8's async global_load_lds path reverted (162 MB phantom writes, 85 us).

typedef __attribute__((ext_vector_type(8))) short bf16x8;   // 8 bf16 (4 VGPRs)
typedef __attribute__((ext_vector_type(4))) float f32x4;    // MFMA C/D frag

__device__ __forceinline__ unsigned short f2bf(float x) {
  unsigned int u = __float_as_uint(x);
  u += 0x7fffu + ((u >> 16) & 1u);
  return (unsigned short)(u >> 16);
}

// W [K=256][H=128] fp32 row-major -> Wt [H=128][K=256] bf16 (once, to ws).
__global__ void sage_prep_wt(const float* __restrict__ W,
                             unsigned short* __restrict__ Wt) {
  int tid = blockIdx.x * blockDim.x + threadIdx.x;   // 0..8191 (float4 units)
  float4 v = ((const float4*)W)[tid];
  int flat = tid << 2;
  int k = flat >> 7;          // / H
  int h = flat & 127;         // % H
  Wt[(h + 0) * 256 + k] = f2bf(v.x);
  Wt[(h + 1) * 256 + k] = f2bf(v.y);
  Wt[(h + 2) * 256 + k] = f2bf(v.z);
  Wt[(h + 3) * 256 + k] = f2bf(v.w);
}

__global__ __launch_bounds__(512, 6)
void sage_fused6(const int* __restrict__ nodes,
                 const int* __restrict__ neigh,
                 const float* __restrict__ feat,
                 const unsigned short* __restrict__ Wt,
                 float* __restrict__ out, int B)
{
  constexpr int K = 256, H = 128, S = 10;
  constexpr int TILE = 32;
  constexpr int STR = K + 8;                   // 264 elems = 528 B rows (bank shift 4)
  __shared__ unsigned short Clds[TILE * STR];  // 16.9 KB
  __shared__ int idxs[TILE * 11];              // [r*11]=node, [r*11+1+s]=neigh (1.4 KB)

  const int t = threadIdx.x;
  const int block0 = blockIdx.x * TILE;

  // ---- Phase 0: stage the block's indices (contiguous global reads) ----
  if (t < TILE * S) {                          // 320 neigh entries
    const long g = (long)block0 * S + t;
    int v = (g < (long)B * S) ? neigh[g] : 0;
    idxs[(t / S) * 11 + 1 + (t % S)] = v;
  } else if (t < TILE * S + TILE) {            // 32 node entries
    const int r = t - TILE * S;
    const int b = block0 + r;
    idxs[r * 11] = (b < B) ? nodes[b] : 0;
  }
  __syncthreads();

  // ---- Phase 1: gather self + mean(neigh) -> LDS tile (bf16) ----
  {
    const int r   = t >> 4;     // 0..31
    const int sub = t & 15;     // 16 threads/row (R3/R6 geometry)
    const int b   = block0 + r;
    unsigned short* crow = &Clds[r * STR];
    if (b < B) {
      const float4* f4 = (const float4*)feat;   // feature row = 32 float4
      const int* myidx = &idxs[r * 11];         // broadcast ds_read per 16 lanes
      const long srow = (long)myidx[0] * 32;
      float4 s0 = f4[srow + sub];               // elems 4sub..4sub+3
      float4 s1 = f4[srow + 16 + sub];          // elems 64+4sub..

      float ax0=0.f, ay0=0.f, az0=0.f, aw0=0.f;
      float ax1=0.f, ay1=0.f, az1=0.f, aw1=0.f;
#pragma unroll
      for (int s = 0; s < S; ++s) {
        const long nrow = (long)myidx[1 + s] * 32;
        float4 v0 = f4[nrow + sub];
        float4 v1 = f4[nrow + 16 + sub];
        ax0 += v0.x; ay0 += v0.y; az0 += v0.z; aw0 += v0.w;
        ax1 += v1.x; ay1 += v1.y; az1 += v1.z; aw1 += v1.w;
      }
      ushort4 o;
      o.x = f2bf(s0.x); o.y = f2bf(s0.y); o.z = f2bf(s0.z); o.w = f2bf(s0.w);
      *(ushort4*)&crow[4 * sub] = o;
      o.x = f2bf(s1.x); o.y = f2bf(s1.y); o.z = f2bf(s1.z); o.w = f2bf(s1.w);
      *(ushort4*)&crow[64 + 4 * sub] = o;
      o.x = f2bf(ax0 * 0.1f); o.y = f2bf(ay0 * 0.1f);
      o.z = f2bf(az0 * 0.1f); o.w = f2bf(aw0 * 0.1f);
      *(ushort4*)&crow[128 + 4 * sub] = o;
      o.x = f2bf(ax1 * 0.1f); o.y = f2bf(ay1 * 0.1f);
      o.z = f2bf(az1 * 0.1f); o.w = f2bf(aw1 * 0.1f);
      *(ushort4*)&crow[192 + 4 * sub] = o;
    } else {
      ushort4 z; z.x = z.y = z.z = z.w = 0;
      *(ushort4*)&crow[4 * sub] = z;
      *(ushort4*)&crow[64 + 4 * sub] = z;
      *(ushort4*)&crow[128 + 4 * sub] = z;
      *(ushort4*)&crow[192 + 4 * sub] = z;
    }
  }
  __syncthreads();
  __builtin_amdgcn_sched_barrier(0);   // keep Wt loads out of phase-1 lifetime

  // ---- Phase 2: 8 waves x (32 rows x 16 cols) MFMA ----
  const int lane = t & 63;
  const int wave = t >> 6;
  const int m    = lane & 15;
  const int quad = lane >> 4;
  const int cbase = wave * 16;      // 8 waves x 16 = 128 cols

  bf16x8 bfrag[8];
#pragma unroll
  for (int ks = 0; ks < 8; ++ks)
    bfrag[ks] = *(const bf16x8*)&Wt[(cbase + m) * K + ks * 32 + quad * 8];

  f32x4 acc0 = {0.f, 0.f, 0.f, 0.f};
  f32x4 acc1 = {0.f, 0.f, 0.f, 0.f};
#pragma unroll
  for (int ks = 0; ks < 8; ++ks) {
    const int koff = ks * 32 + quad * 8;
    bf16x8 a0 = *(const bf16x8*)&Clds[(m     ) * STR + koff];
    bf16x8 a1 = *(const bf16x8*)&Clds[(16 + m) * STR + koff];
    acc0 = __builtin_amdgcn_mfma_f32_16x16x32_bf16(a0, bfrag[ks], acc0, 0, 0, 0);
    acc1 = __builtin_amdgcn_mfma_f32_16x16x32_bf16(a1, bfrag[ks], acc1, 0, 0, 0);
  }

  // C/D layout: col = lane&15, row = quad*4 + reg (verified m89/m91)
#pragma unroll
  for (int reg = 0; reg < 4; ++reg) {
    const int row0 = quad * 4 + reg;
    const int gb0 = block0 + row0;
    const int gb1 = gb0 + 16;
    if (gb0 < B) out[(size_t)gb0 * H + cbase + m] = fmaxf(acc0[reg], 0.0f);
    if (gb1 < B) out[(size_t)gb1 * H + cbase + m] = fmaxf(acc1[reg], 0.0f);
  }
}

extern "C" void kernel_launch(void* const* d_in, const int* in_sizes, int n_in,
                              void* d_out, int out_size, void* d_ws, size_t ws_size,
                              hipStream_t stream) {
  const int*   nodes = (const int*)d_in[0];
  const int*   neigh = (const int*)d_in[1];
  const float* feat  = (const float*)d_in[2];
  const float* W     = (const float*)d_in[3];
  float*       out   = (float*)d_out;
  const int B = in_sizes[0];                       // 50000

  unsigned short* Wt = (unsigned short*)d_ws;      // 64 KB
  sage_prep_wt<<<32, 256, 0, stream>>>(W, Wt);
  const int grid = (B + 31) / 32;                  // 1563
  sage_fused6<<<grid, 512, 0, stream>>>(nodes, neigh, feat, Wt, out, B);
}